// Round 16
// baseline (72.300 us; speedup 1.0000x reference)
//
#include <hip/hip_runtime.h>
#include <math.h>

// Problem constants
#define NB 128     // batch
#define NR 1152    // routes
#define NC 10      // capsules
#define NPC 48     // blocks per capsule (24 rch x 2 bh)

typedef __attribute__((ext_vector_type(8))) short bf16x8;
typedef __attribute__((ext_vector_type(16))) float f32x16;

__device__ __forceinline__ unsigned pk_bf16(float a, float b) {
    unsigned r;
    asm("v_cvt_pk_bf16_f32 %0, %1, %2" : "=v"(r) : "v"(a), "v"(b));
    return r;
}

union UF { uint4 q; unsigned u[4]; bf16x8 v; };

// ------------------------------------------------------------------
// pass_w (r15 structure, 2x blocks): fused bf16x3 + 32x32x16 MFMA pred +
// route reduction + folded merge/squash epilogue via per-capsule handshake.
// Grid 480 = (10 c x 24 rch x 2 bh), XCD-chunked: XCD k owns rch [3k,3k+3)
// -> per-XCD W slice 2.95 MB (L2-fit). 512 thr = 8 waves = 4 h-route-
// quarters x 2 bp; each wave: 12 routes x ONE 32-batch group
// (bq = bh*64 + bp*32 + lane) -> per-wave state halved vs r15, waves 2x.
// A = W (M=o), B = x (N=b). C: col(l&31)=b, row(reg&3)+8*(reg>>2)+4*hi1=o.
// MODE 0: uniform sum; x direct; owner lanes write xts bf16 planes; bh==0,
//         bp==0 waves store W bf16 hi/lo fragments to wts (r15-proven).
// MODE 1/2: W = 2 coalesced uint4 loads from wts; x from xts; d = pred.ov,
//         e = exp(d-20), Z += e, acc += e*pred.
// Epilogue: 4-slice LDS merge of the block's [64b][32o] half-tile ->
// agent atomicAdd into per-capsule 16KB accumulator; handshake cnt==47;
// last block squashes full capsule, writes oacc (M0) / += (M1) / dout (M2).
// ------------------------------------------------------------------
template<int MODE>
__global__ __launch_bounds__(512, 2) void pass_w(const float* __restrict__ x,
                                                 const float* __restrict__ W,
                                                 unsigned* __restrict__ xts,
                                                 unsigned* __restrict__ wts,
                                                 float* __restrict__ oacc,
                                                 float* __restrict__ dout,
                                                 float* __restrict__ sbuf,
                                                 float* __restrict__ zbuf,
                                                 int* __restrict__ cnt)
{
    __shared__ float lds[16384];   // 64 KB -> pins 2 blocks/CU (r15 VGPR regime)
    __shared__ int lastFlag;
    const int pb = blockIdx.x;
    const int lin = (pb & 7) * 60 + (pb >> 3);   // chunked XCD swizzle (480 = 8*60)
    const int c   = lin % 10;
    const int g   = lin / 10;                    // 0..47
    const int bh  = g & 1;
    const int rch = g >> 1;                      // 0..23
    const int t = threadIdx.x;
    const int w = t >> 6, l = t & 63;
    const int h = w >> 1, bp = w & 1;
    const int lo5 = l & 31, hi1 = l >> 5;
    const int r0 = rch * 48 + h * 12;
    const int bq = bh * 64 + bp * 32 + lo5;      // this lane's global batch

    if (MODE >= 1) {
        // stage only this block's 64-batch slice of oacc
        for (int idx = t; idx < 2048; idx += 512)
            lds[(idx >> 5) * 33 + (idx & 31)] =
                oacc[(size_t)c * 4096 + bh * 2048 + idx];
    }
    __syncthreads();

    float ov[16];
    if (MODE >= 1) {
#pragma unroll
        for (int j = 0; j < 16; ++j) {
            int orow = (j & 3) + 8 * (j >> 2) + 4 * hi1;
            ov[j] = lds[(bp * 32 + lo5) * 33 + orow];
        }
    }

    f32x16 acc, zz;
#pragma unroll
    for (int j = 0; j < 16; ++j) { acc[j] = 0.f; zz[j] = 0.f; }
    float Z = 0.f;

    // W element (r, i=hi1*8+j, o=lo5)
    const float* wb = W + ((size_t)(c * NR + r0) * 16 + hi1 * 8) * 32 + lo5;
    // direct-x pointer (MODE 0)
    const float* xp = x + ((size_t)bq * NR + r0) * 16 + hi1 * 8;
    // xts uint4-unit addressing: ((r*2+hi1)*2 + plane)*128 + b
    uint4* xt4 = (uint4*)xts;
    // wts uint4-unit addressing: ((c*NR+r)*2 + plane)*64 + l
    uint4* wt4 = (uint4*)wts;

#pragma unroll 4
    for (int rr = 0; rr < 12; ++rr) {
        UF Ah, Al, Xh, Xl;
        const size_t wrow = (size_t)(c * NR + r0 + rr) * 2;
        if (MODE == 0) {
            // ---- W fragment: 8 lane-coalesced f32 -> hi/lo bf16 planes ----
            float wv[8];
#pragma unroll
            for (int j = 0; j < 8; ++j) wv[j] = wb[(size_t)rr * 512 + j * 32];
#pragma unroll
            for (int j = 0; j < 4; ++j) Ah.u[j] = pk_bf16(wv[2*j], wv[2*j+1]);
#pragma unroll
            for (int j = 0; j < 4; ++j) {
                float g0 = __uint_as_float(Ah.u[j] << 16);
                float g1 = __uint_as_float(Ah.u[j] & 0xffff0000u);
                Al.u[j] = pk_bf16(wv[2*j] - g0, wv[2*j+1] - g1);
            }
            // store MFMA-ready W planes once per (c,r): bh==0, bp==0 waves
            if (bh == 0 && bp == 0) {
                wt4[wrow * 64 + l]       = Ah.q;
                wt4[(wrow + 1) * 64 + l] = Al.q;
            }
        } else {
            Ah.q = wt4[wrow * 64 + l];
            Al.q = wt4[(wrow + 1) * 64 + l];
        }
        // ---- x fragment ----
        const size_t rb4 = ((size_t)((r0 + rr) * 2 + hi1) * 2) * 128;
        if (MODE == 0) {
            float4 u0 = *(const float4*)(xp + rr * 16);
            float4 u1 = *(const float4*)(xp + rr * 16 + 4);
            float xv[8] = {u0.x,u0.y,u0.z,u0.w, u1.x,u1.y,u1.z,u1.w};
#pragma unroll
            for (int j = 0; j < 4; ++j) Xh.u[j] = pk_bf16(xv[2*j], xv[2*j+1]);
#pragma unroll
            for (int j = 0; j < 4; ++j) {
                float g0 = __uint_as_float(Xh.u[j] << 16);
                float g1 = __uint_as_float(Xh.u[j] & 0xffff0000u);
                Xl.u[j] = pk_bf16(xv[2*j] - g0, xv[2*j+1] - g1);
            }
            // distributed xts write (this block's batches only)
            if (((h * 12 + rr) % 10) == c) {
                xt4[rb4 + bq]       = Xh.q;
                xt4[rb4 + 128 + bq] = Xl.q;
            }
            acc = __builtin_amdgcn_mfma_f32_32x32x16_bf16(Ah.v, Xh.v, acc, 0, 0, 0);
            acc = __builtin_amdgcn_mfma_f32_32x32x16_bf16(Al.v, Xh.v, acc, 0, 0, 0);
            acc = __builtin_amdgcn_mfma_f32_32x32x16_bf16(Ah.v, Xl.v, acc, 0, 0, 0);
        } else {
            Xh.q = xt4[rb4 + bq];
            Xl.q = xt4[rb4 + 128 + bq];
            f32x16 q;
            q = __builtin_amdgcn_mfma_f32_32x32x16_bf16(Ah.v, Xh.v, zz, 0, 0, 0);
            q = __builtin_amdgcn_mfma_f32_32x32x16_bf16(Al.v, Xh.v, q, 0, 0, 0);
            q = __builtin_amdgcn_mfma_f32_32x32x16_bf16(Ah.v, Xl.v, q, 0, 0, 0);
            float d0 = 0.f, d1 = 0.f;
#pragma unroll
            for (int j = 0; j < 8; ++j) {
                d0 = fmaf(q[2*j],   ov[2*j],   d0);
                d1 = fmaf(q[2*j+1], ov[2*j+1], d1);
            }
            float d = d0 + d1;
            d += __shfl_xor(d, 32);    // combine k-halves (same batch column)
            float e = __expf(d - 20.0f);
            Z += e;
#pragma unroll
            for (int j = 0; j < 16; ++j) acc[j] = fmaf(e, q[j], acc[j]);
        }
    }

    // ---- 8-wave LDS merge of [64b][32o] half-tile (4 h-slices) ----
    const int bl = bp * 32 + lo5;   // local batch 0..63
    __syncthreads();
#pragma unroll
    for (int j = 0; j < 16; ++j) {
        int orow = (j & 3) + 8 * (j >> 2) + 4 * hi1;
        lds[h * 2048 + bl * 32 + (orow ^ lo5)] = acc[j];
    }
    if (MODE >= 1 && l < 32) lds[8192 + h * 64 + bp * 32 + lo5] = Z;
    __syncthreads();
    // half-tile -> per-capsule accumulator via agent-scope atomicAdd
    float* sc = sbuf + (size_t)c * 4096;
#pragma unroll
    for (int k = 0; k < 4; ++k) {
        int idx = t + 512 * k;          // 2048 elems
        int b2 = idx >> 5, o = idx & 31;
        float s = 0.f;
#pragma unroll
        for (int hh = 0; hh < 4; ++hh)
            s += lds[hh * 2048 + b2 * 32 + (o ^ (b2 & 31))];
        (void)__hip_atomic_fetch_add(sc + (size_t)(bh * 64 + b2) * 32 + o, s,
                                     __ATOMIC_RELAXED, __HIP_MEMORY_SCOPE_AGENT);
    }
    if (MODE >= 1 && t < 64) {
        float z = lds[8192 + t] + lds[8256 + t] + lds[8320 + t] + lds[8384 + t];
        (void)__hip_atomic_fetch_add(zbuf + (size_t)c * 128 + bh * 64 + t, z,
                                     __ATOMIC_RELAXED, __HIP_MEMORY_SCOPE_AGENT);
    }

    // ---- completion handshake (r10/r15-proven) ----
    __syncthreads();   // per-wave vmcnt(0) drain -> adds at coherence point
    if (t == 0) {
        int old = __hip_atomic_fetch_add(&cnt[c], 1,
                                         __ATOMIC_RELAXED, __HIP_MEMORY_SCOPE_AGENT);
        lastFlag = (old == NPC - 1) ? 1 : 0;
    }
    __syncthreads();
    if (!lastFlag) return;

    // ===== merger block: read 16KB summed s (+512B z), squash, write =====
    if (MODE >= 1) {
        if (t < NB) {
            lds[8192 + t] = __hip_atomic_load(zbuf + (size_t)c * 128 + t,
                                              __ATOMIC_RELAXED, __HIP_MEMORY_SCOPE_AGENT);
        }
        __syncthreads();
    }
    float sv[8];
    float pn = 0.f;
#pragma unroll
    for (int k = 0; k < 8; ++k) {
        int idx = t + 512 * k;          // o = t&31, b-groups
        float s = __hip_atomic_load(sc + idx, __ATOMIC_RELAXED,
                                    __HIP_MEMORY_SCOPE_AGENT);
        float v = (MODE == 0) ? s * (1.0f / 1152.0f) : s / lds[8192 + (idx >> 5)];
        sv[k] = v;
        pn = fmaf(v, v, pn);
    }
    lds[(t >> 5) * 33 + (t & 31)] = pn;   // 16 groups x 32 o
    __syncthreads();
    if (t < 32) {
        float n2 = 0.f;
#pragma unroll
        for (int m = 0; m < 16; ++m) n2 += lds[m * 33 + t];
        lds[1024 + t] = sqrtf(n2) / (1.0f + n2);   // (n2/(1+n2))/sqrt(n2)
    }
    __syncthreads();
    const float ff = lds[1024 + (t & 31)];
#pragma unroll
    for (int k = 0; k < 8; ++k) {
        int idx = t + 512 * k;
        float v = sv[k] * ff;
        if (MODE == 0)      oacc[(size_t)c * 4096 + idx] = v;
        else if (MODE == 1) oacc[(size_t)c * 4096 + idx] += v;
        else                dout[(size_t)c * 4096 + idx] = v;
    }
}

// ------------------------------------------------------------------
extern "C" void kernel_launch(void* const* d_in, const int* in_sizes, int n_in,
                              void* d_out, int out_size, void* d_ws, size_t ws_size,
                              hipStream_t stream)
{
    (void)in_sizes; (void)n_in; (void)out_size; (void)ws_size;
    const float* x = (const float*)d_in[0];
    const float* W = (const float*)d_in[1];
    float* wsf  = (float*)d_ws;
    float* outf = (float*)d_out;

    // ws layout (32-bit units):
    // xts 2,359,296 | wts 5,898,240 | sbuf 3x40,960 | zbuf 3x1,280 | cnt 32 | oacc
    unsigned* xts = (unsigned*)d_ws;
    unsigned* wts = (unsigned*)d_ws + 2359296;
    float* sb   = wsf + 2359296 + 5898240;
    float* zb   = sb + 3 * 40960;
    int*   cnt  = (int*)(zb + 3 * 1280);
    float* oacc = (float*)(cnt + 32);

    // zero accumulators + counters (ws is poisoned to 0xAA once)
    hipMemsetAsync(sb, 0, (size_t)(3 * 40960 + 3 * 1280 + 32) * 4, stream);

    // iter 0: uniform; owner lanes emit xts planes + wts W-fragments; folded squash
    pass_w<0><<<480, 512, 0, stream>>>(x, W, xts, wts, oacc, nullptr,
                                       sb, zb, cnt);
    // iter 1: softmax(pred . out0); folded squash-accumulate
    pass_w<1><<<480, 512, 0, stream>>>(x, W, xts, wts, oacc, nullptr,
                                       sb + 40960, zb + 1280, cnt + NC);
    // iter 2: softmax(pred . (out0+out1)); folded squash -> d_out
    pass_w<2><<<480, 512, 0, stream>>>(x, W, xts, wts, oacc, outf,
                                       sb + 2 * 40960, zb + 2 * 1280, cnt + 2 * NC);
}

// Round 17
// 66.812 us; speedup vs baseline: 1.0821x; 1.0821x over previous
//
#include <hip/hip_runtime.h>
#include <math.h>

// Problem constants
#define NB 128     // batch
#define NR 1152    // routes
#define NC 10      // capsules
#define NCHK 24    // chunks per capsule (route-chunks of 48)

typedef __attribute__((ext_vector_type(8))) short bf16x8;
typedef __attribute__((ext_vector_type(16))) float f32x16;

__device__ __forceinline__ unsigned pk_bf16(float a, float b) {
    unsigned r;
    asm("v_cvt_pk_bf16_f32 %0, %1, %2" : "=v"(r) : "v"(a), "v"(b));
    return r;
}

union UF { uint4 q; unsigned u[4]; bf16x8 v; };

// ------------------------------------------------------------------
// pass_z (round-15 proven BEST: r10 structure + wts precompute + unroll 4):
// fused bf16x3 + 32x32x16 MFMA pred + route reduction + folded
// merge/squash epilogue via per-capsule atomic handshake.
// Grid 240 = (10 c x 24 rch of 48 routes), XCD-chunked. 512 thr = 8 waves:
// wave = (h = route-quarter of 12, bp = batch-half of 64).
// A = W (M=o), B = x (N=b). C: col(l&31)=b, row(reg&3)+8*(reg>>2)+4*hi1=o.
// MODE 0: uniform sum; x read direct; owner lanes write xts bf16 planes
//         (plain stores; visible to later DISPATCHES); bp==0 waves also
//         store the W bf16 hi/lo fragments to wts (2 uint4/lane/route).
// MODE 1/2: W fragment = 2 coalesced uint4 loads from wts (replaces 8
//         strided dword loads + ~25 convert VALU); x fragments from xts;
//         d = pred.ov, e = exp(d-20), Z += e, acc += e*pred.
// Epilogue: LDS 4-slice merge -> agent atomicAdd into per-capsule 16KB
// accumulator; __syncthreads (vmcnt drain); fetch_add handshake; last
// block (old==23) reads 16KB sums (agent atomic loads), squashes, writes
// oacc (M0) / oacc+= (M1) / dout (M2).
// ------------------------------------------------------------------
template<int MODE>
__global__ __launch_bounds__(512, 2) void pass_z(const float* __restrict__ x,
                                                 const float* __restrict__ W,
                                                 unsigned* __restrict__ xts,
                                                 unsigned* __restrict__ wts,
                                                 float* __restrict__ oacc,
                                                 float* __restrict__ dout,
                                                 float* __restrict__ sbuf,
                                                 float* __restrict__ zbuf,
                                                 int* __restrict__ cnt)
{
    __shared__ float lds[16384];   // 64 KB
    __shared__ int lastFlag;
    const int pb = blockIdx.x;
    const int lin = (pb & 7) * 30 + (pb >> 3);   // chunked XCD swizzle (240 = 8*30)
    const int rch = lin / 10;
    const int c   = lin - rch * 10;
    const int t = threadIdx.x;
    const int w = t >> 6, l = t & 63;
    const int h = w >> 1, bp = w & 1;
    const int lo5 = l & 31, hi1 = l >> 5;
    const int r0 = rch * 48 + h * 12;

    if (MODE >= 1) {
        for (int idx = t; idx < 4096; idx += 512)
            lds[(idx >> 5) * 33 + (idx & 31)] = oacc[(size_t)c * 4096 + idx];
    }
    __syncthreads();

    float ov0[16], ov1[16];
    if (MODE >= 1) {
#pragma unroll
        for (int j = 0; j < 16; ++j) {
            int orow = (j & 3) + 8 * (j >> 2) + 4 * hi1;
            ov0[j] = lds[(bp * 64 + lo5) * 33 + orow];
            ov1[j] = lds[(bp * 64 + 32 + lo5) * 33 + orow];
        }
    }

    f32x16 acc0, acc1, zz;
#pragma unroll
    for (int j = 0; j < 16; ++j) { acc0[j] = 0.f; acc1[j] = 0.f; zz[j] = 0.f; }
    float Z0 = 0.f, Z1 = 0.f;

    // W element (r, i=hi1*8+j, o=lo5)
    const float* wb  = W + ((size_t)(c * NR + r0) * 16 + hi1 * 8) * 32 + lo5;
    // direct-x pointers (MODE 0)
    const float* xp0 = x + ((size_t)(bp * 64 + lo5) * NR + r0) * 16 + hi1 * 8;
    const float* xp1 = x + ((size_t)(bp * 64 + 32 + lo5) * NR + r0) * 16 + hi1 * 8;
    // xts uint4-unit addressing: ((r*2+hi1)*2 + plane)*128 + b
    uint4* xt4 = (uint4*)xts;
    // wts uint4-unit addressing: ((c*NR+r)*2 + plane)*64 + l
    uint4* wt4 = (uint4*)wts;
    const int bq0 = bp * 64 + lo5, bq1 = bq0 + 32;

#pragma unroll 4
    for (int rr = 0; rr < 12; ++rr) {
        UF Ah, Al, Xh0, Xl0, Xh1, Xl1;
        const size_t wrow = (size_t)(c * NR + r0 + rr) * 2;
        if (MODE == 0) {
            // ---- W fragment: 8 lane-coalesced f32 -> hi/lo bf16 planes ----
            float wv[8];
#pragma unroll
            for (int j = 0; j < 8; ++j) wv[j] = wb[(size_t)rr * 512 + j * 32];
#pragma unroll
            for (int j = 0; j < 4; ++j) Ah.u[j] = pk_bf16(wv[2*j], wv[2*j+1]);
#pragma unroll
            for (int j = 0; j < 4; ++j) {
                float g0 = __uint_as_float(Ah.u[j] << 16);
                float g1 = __uint_as_float(Ah.u[j] & 0xffff0000u);
                Al.u[j] = pk_bf16(wv[2*j] - g0, wv[2*j+1] - g1);
            }
            // store MFMA-ready W planes (once per (c,r): bp==0 waves only)
            if (bp == 0) {
                wt4[wrow * 64 + l]       = Ah.q;
                wt4[(wrow + 1) * 64 + l] = Al.q;
            }
        } else {
            // ---- W fragment: 2 coalesced uint4 loads (1KB/wave each) ----
            Ah.q = wt4[wrow * 64 + l];
            Al.q = wt4[(wrow + 1) * 64 + l];
        }
        // ---- x fragments ----
        const size_t rb4 = ((size_t)((r0 + rr) * 2 + hi1) * 2) * 128;
        if (MODE == 0) {
            float4 u0 = *(const float4*)(xp0 + rr * 16);
            float4 u1 = *(const float4*)(xp0 + rr * 16 + 4);
            float4 v0 = *(const float4*)(xp1 + rr * 16);
            float4 v1 = *(const float4*)(xp1 + rr * 16 + 4);
            float xv0[8] = {u0.x,u0.y,u0.z,u0.w, u1.x,u1.y,u1.z,u1.w};
            float xv1[8] = {v0.x,v0.y,v0.z,v0.w, v1.x,v1.y,v1.z,v1.w};
#pragma unroll
            for (int j = 0; j < 4; ++j) Xh0.u[j] = pk_bf16(xv0[2*j], xv0[2*j+1]);
#pragma unroll
            for (int j = 0; j < 4; ++j) {
                float g0 = __uint_as_float(Xh0.u[j] << 16);
                float g1 = __uint_as_float(Xh0.u[j] & 0xffff0000u);
                Xl0.u[j] = pk_bf16(xv0[2*j] - g0, xv0[2*j+1] - g1);
            }
#pragma unroll
            for (int j = 0; j < 4; ++j) Xh1.u[j] = pk_bf16(xv1[2*j], xv1[2*j+1]);
#pragma unroll
            for (int j = 0; j < 4; ++j) {
                float g0 = __uint_as_float(Xh1.u[j] << 16);
                float g1 = __uint_as_float(Xh1.u[j] & 0xffff0000u);
                Xl1.u[j] = pk_bf16(xv1[2*j] - g0, xv1[2*j+1] - g1);
            }
            // distributed xts write: this block owns routes (h*12+rr)%10 == c
            if (((h * 12 + rr) % 10) == c) {
                xt4[rb4 + bq0]       = Xh0.q;
                xt4[rb4 + 128 + bq0] = Xl0.q;
                xt4[rb4 + bq1]       = Xh1.q;
                xt4[rb4 + 128 + bq1] = Xl1.q;
            }
        } else {
            Xh0.q = xt4[rb4 + bq0];
            Xl0.q = xt4[rb4 + 128 + bq0];
            Xh1.q = xt4[rb4 + bq1];
            Xl1.q = xt4[rb4 + 128 + bq1];
        }

        if (MODE == 0) {
            acc0 = __builtin_amdgcn_mfma_f32_32x32x16_bf16(Ah.v, Xh0.v, acc0, 0, 0, 0);
            acc0 = __builtin_amdgcn_mfma_f32_32x32x16_bf16(Al.v, Xh0.v, acc0, 0, 0, 0);
            acc0 = __builtin_amdgcn_mfma_f32_32x32x16_bf16(Ah.v, Xl0.v, acc0, 0, 0, 0);
            acc1 = __builtin_amdgcn_mfma_f32_32x32x16_bf16(Ah.v, Xh1.v, acc1, 0, 0, 0);
            acc1 = __builtin_amdgcn_mfma_f32_32x32x16_bf16(Al.v, Xh1.v, acc1, 0, 0, 0);
            acc1 = __builtin_amdgcn_mfma_f32_32x32x16_bf16(Ah.v, Xl1.v, acc1, 0, 0, 0);
        } else {
            f32x16 q0, q1;
            q0 = __builtin_amdgcn_mfma_f32_32x32x16_bf16(Ah.v, Xh0.v, zz, 0, 0, 0);
            q1 = __builtin_amdgcn_mfma_f32_32x32x16_bf16(Ah.v, Xh1.v, zz, 0, 0, 0);
            q0 = __builtin_amdgcn_mfma_f32_32x32x16_bf16(Al.v, Xh0.v, q0, 0, 0, 0);
            q1 = __builtin_amdgcn_mfma_f32_32x32x16_bf16(Al.v, Xh1.v, q1, 0, 0, 0);
            q0 = __builtin_amdgcn_mfma_f32_32x32x16_bf16(Ah.v, Xl0.v, q0, 0, 0, 0);
            q1 = __builtin_amdgcn_mfma_f32_32x32x16_bf16(Ah.v, Xl1.v, q1, 0, 0, 0);
            float d0 = 0.f, d1 = 0.f;
#pragma unroll
            for (int j = 0; j < 16; ++j) {
                d0 = fmaf(q0[j], ov0[j], d0);
                d1 = fmaf(q1[j], ov1[j], d1);
            }
            d0 += __shfl_xor(d0, 32);
            d1 += __shfl_xor(d1, 32);
            float e0 = __expf(d0 - 20.0f);
            float e1 = __expf(d1 - 20.0f);
            Z0 += e0; Z1 += e1;
#pragma unroll
            for (int j = 0; j < 16; ++j) {
                acc0[j] = fmaf(e0, q0[j], acc0[j]);
                acc1[j] = fmaf(e1, q1[j], acc1[j]);
            }
        }
    }

    // ---- 8-wave LDS merge (4 h-slices; b-halves disjoint) ----
    const int b0 = bp * 64 + lo5, b1 = b0 + 32;
    __syncthreads();
#pragma unroll
    for (int j = 0; j < 16; ++j) {
        int orow = (j & 3) + 8 * (j >> 2) + 4 * hi1;
        lds[h * 4096 + b0 * 32 + (orow ^ lo5)] = acc0[j];
        lds[h * 4096 + b1 * 32 + (orow ^ lo5)] = acc1[j];
    }
    __syncthreads();
    // chunk partial -> per-capsule accumulator via agent-scope atomicAdd
    float* sc = sbuf + (size_t)c * 4096;
    for (int idx = t; idx < 4096; idx += 512) {
        int b = idx >> 5, o = idx & 31;
        float s = 0.f;
#pragma unroll
        for (int hh = 0; hh < 4; ++hh)
            s += lds[hh * 4096 + b * 32 + (o ^ (b & 31))];
        (void)__hip_atomic_fetch_add(sc + idx, s, __ATOMIC_RELAXED,
                                     __HIP_MEMORY_SCOPE_AGENT);
    }
    if (MODE >= 1) {
        __syncthreads();
        if (l < 32) {
            lds[h * 128 + bp * 64 + lo5] = Z0;
            lds[h * 128 + bp * 64 + 32 + lo5] = Z1;
        }
        __syncthreads();
        if (t < 128) {
            float z = lds[t] + lds[128 + t] + lds[256 + t] + lds[384 + t];
            (void)__hip_atomic_fetch_add(zbuf + (size_t)c * 128 + t, z,
                                         __ATOMIC_RELAXED, __HIP_MEMORY_SCOPE_AGENT);
        }
    }

    // ---- completion handshake ----
    __syncthreads();   // per-wave vmcnt(0) drain -> all adds at coherence point
    if (t == 0) {
        int old = __hip_atomic_fetch_add(&cnt[c], 1,
                                         __ATOMIC_RELAXED, __HIP_MEMORY_SCOPE_AGENT);
        lastFlag = (old == NCHK - 1) ? 1 : 0;
    }
    __syncthreads();
    if (!lastFlag) return;

    // ===== merger block: read 16KB summed s (+512B z), squash, write =====
    if (MODE >= 1) {
        if (t < NB) {
            lds[8192 + t] = __hip_atomic_load(zbuf + (size_t)c * 128 + t,
                                              __ATOMIC_RELAXED, __HIP_MEMORY_SCOPE_AGENT);
        }
        __syncthreads();
    }
    float sv[8];
    float pn = 0.f;
#pragma unroll
    for (int k = 0; k < 8; ++k) {
        int idx = t + 512 * k;          // o = t&31, b-groups
        float s = __hip_atomic_load(sc + idx, __ATOMIC_RELAXED,
                                    __HIP_MEMORY_SCOPE_AGENT);
        float v = (MODE == 0) ? s * (1.0f / 1152.0f) : s / lds[8192 + (idx >> 5)];
        sv[k] = v;
        pn = fmaf(v, v, pn);
    }
    lds[(t >> 5) * 33 + (t & 31)] = pn;   // 16 groups x 32 o
    __syncthreads();
    if (t < 32) {
        float n2 = 0.f;
#pragma unroll
        for (int m = 0; m < 16; ++m) n2 += lds[m * 33 + t];
        lds[1024 + t] = sqrtf(n2) / (1.0f + n2);   // (n2/(1+n2))/sqrt(n2)
    }
    __syncthreads();
    const float ff = lds[1024 + (t & 31)];
#pragma unroll
    for (int k = 0; k < 8; ++k) {
        int idx = t + 512 * k;
        float v = sv[k] * ff;
        if (MODE == 0)      oacc[(size_t)c * 4096 + idx] = v;
        else if (MODE == 1) oacc[(size_t)c * 4096 + idx] += v;
        else                dout[(size_t)c * 4096 + idx] = v;
    }
}

// ------------------------------------------------------------------
extern "C" void kernel_launch(void* const* d_in, const int* in_sizes, int n_in,
                              void* d_out, int out_size, void* d_ws, size_t ws_size,
                              hipStream_t stream)
{
    (void)in_sizes; (void)n_in; (void)out_size; (void)ws_size;
    const float* x = (const float*)d_in[0];
    const float* W = (const float*)d_in[1];
    float* wsf  = (float*)d_ws;
    float* outf = (float*)d_out;

    // ws layout (32-bit units):
    // xts 2,359,296 | wts 5,898,240 | sbuf 3x40,960 | zbuf 3x1,280 | cnt 32 | oacc
    unsigned* xts = (unsigned*)d_ws;
    unsigned* wts = (unsigned*)d_ws + 2359296;
    float* sb   = wsf + 2359296 + 5898240;
    float* zb   = sb + 3 * 40960;
    int*   cnt  = (int*)(zb + 3 * 1280);
    float* oacc = (float*)(cnt + 32);

    // zero accumulators + counters (ws is poisoned to 0xAA once)
    hipMemsetAsync(sb, 0, (size_t)(3 * 40960 + 3 * 1280 + 32) * 4, stream);

    // iter 0: uniform; owner lanes emit xts planes + wts W-fragments; folded squash
    pass_z<0><<<240, 512, 0, stream>>>(x, W, xts, wts, oacc, nullptr,
                                       sb, zb, cnt);
    // iter 1: softmax(pred . out0); folded squash-accumulate
    pass_z<1><<<240, 512, 0, stream>>>(x, W, xts, wts, oacc, nullptr,
                                       sb + 40960, zb + 1280, cnt + NC);
    // iter 2: softmax(pred . (out0+out1)); folded squash -> d_out
    pass_z<2><<<240, 512, 0, stream>>>(x, W, xts, wts, oacc, outf,
                                       sb + 2 * 40960, zb + 2 * 1280, cnt + 2 * NC);
}